// Round 10
// baseline (380.184 us; speedup 1.0000x reference)
//
#include <hip/hip_runtime.h>

// sparsemax over axis=2 of x[8][16][4096][64] (fp32) — 2-kernel, contiguous.
//
// R9 evidence: contiguous k1 ≈ 52us (vs 96 scattered) — burst-read fix works.
// But k2_newton = 123us, FETCH 92MB, occupancy 6%: ~1% of quarter-columns had
// #{v > qmax-1} > GCAP=64 (low-qmax tail of max-of-1024) -> sentinel -> strided
// 4B/line full-column fallback, ~100us straggler blocks on an empty GPU.
//
// R10: (a) adaptive trim threshold qmax-{1,0.5,0.25} with qthr[] recording;
// K2 validity check (qthr <= gmax-1) makes the strided fallback probability
// ~e^-14 while GCAP stays 64 (ws unchanged ~8.8MB). (b) tau-solve fused into
// the apply kernel (per-slab recompute, x4 redundant, us-scale) -> 2 kernels.
// (c) NT stores for out.
//
// K1: block=(slab,quarter of 1024 rows), 256KB contiguous; wave load = 64
//     consecutive float4 (1KB burst). Per-wave col-max (xor16/32), immediate
//     extract with wave-max-1 threshold into LDS lists, quarter-max adaptive
//     trim -> glist/gcnt/qthr/pmax.
// K2: phase A: per-block Newton (shifted domain z=v-gmax, from-below, exact)
//     for its slab's 64 cols from lists; phase B: contiguous re-read (L3-hot)
//     + relu((x-gmax)-tau) + contiguous NT store.

#define LCAP 192
#define GCAP 64
#define SENT (GCAP + 1000)

typedef float f32x4 __attribute__((ext_vector_type(4)));

// ---------------------------------------------------------------- K1 ----
__global__ __launch_bounds__(1024)
void k1_extract(const float* __restrict__ x,
                float* __restrict__ pmax,    // [ncols][4]
                int*   __restrict__ gcnt,    // [ncols][4]
                float* __restrict__ qthr,    // [ncols][4]
                float* __restrict__ glist)   // [ncols][4][GCAP]
{
    const int b  = blockIdx.x;      // 0..511
    const int bh = b >> 2;          // slab
    const int q  = b & 3;           // quarter (1024 rows)

    const int t   = threadIdx.x;    // 0..1023
    const int l   = t & 63;
    const int wv  = t >> 6;         // 0..15
    const int sub = l >> 4;         // row within 4-row group
    const int d4  = l & 15;         // float4 column

    __shared__ float list[64][LCAP];
    __shared__ int   cnt[64];
    __shared__ int   cnt2[64];
    __shared__ float redbuf[16][64];
    __shared__ float bmaxs[64];

    const f32x4* __restrict__ x4 = reinterpret_cast<const f32x4*>(x);
    // f4 idx: bh*65536 + row*16 + d4 ; row = q*1024 + wv*64 + s*4 + sub
    const size_t base = (size_t)bh * 65536 + (size_t)q * 16384
                      + (size_t)wv * 1024 + (size_t)l;

    if (t < 64) { cnt[t] = 0; cnt2[t] = 0; }
    __syncthreads();

    // contiguous load: each wave inst = 64 consecutive f4 (1KB burst)
    f32x4 c[16];
#pragma unroll
    for (int s = 0; s < 16; ++s)
        c[s] = x4[base + (size_t)s * 64];

    // per-thread max over its 16 rows
    f32x4 m = c[0];
#pragma unroll
    for (int s = 1; s < 16; ++s) {
        m.x = fmaxf(m.x, c[s].x);
        m.y = fmaxf(m.y, c[s].y);
        m.z = fmaxf(m.z, c[s].z);
        m.w = fmaxf(m.w, c[s].w);
    }
    // wave max per col (xor 16,32 keeps d4 class)
#pragma unroll
    for (int mask = 16; mask <= 32; mask <<= 1) {
        m.x = fmaxf(m.x, __shfl_xor(m.x, mask));
        m.y = fmaxf(m.y, __shfl_xor(m.y, mask));
        m.z = fmaxf(m.z, __shfl_xor(m.z, mask));
        m.w = fmaxf(m.w, __shfl_xor(m.w, mask));
    }
    if (sub == 0) {
        redbuf[wv][d4 * 4 + 0] = m.x;
        redbuf[wv][d4 * 4 + 1] = m.y;
        redbuf[wv][d4 * 4 + 2] = m.z;
        redbuf[wv][d4 * 4 + 3] = m.w;
    }

    // immediate extract, wave-local threshold (superset of final support)
    const float Tx = m.x - 1.0f, Ty = m.y - 1.0f, Tz = m.z - 1.0f, Tw = m.w - 1.0f;
    const int c0 = d4 << 2;
#pragma unroll
    for (int s = 0; s < 16; ++s) {
        if (c[s].x > Tx) { int p = atomicAdd(&cnt[c0+0], 1); if (p < LCAP) list[c0+0][p] = c[s].x; }
        if (c[s].y > Ty) { int p = atomicAdd(&cnt[c0+1], 1); if (p < LCAP) list[c0+1][p] = c[s].y; }
        if (c[s].z > Tz) { int p = atomicAdd(&cnt[c0+2], 1); if (p < LCAP) list[c0+2][p] = c[s].z; }
        if (c[s].w > Tw) { int p = atomicAdd(&cnt[c0+3], 1); if (p < LCAP) list[c0+3][p] = c[s].w; }
    }
    __syncthreads();

    // quarter max per col
    if (t < 64) {
        float g = redbuf[0][t];
#pragma unroll
        for (int w = 1; w < 16; ++w) g = fmaxf(g, redbuf[w][t]);
        bmaxs[t] = g;
        pmax[((size_t)bh * 64 + t) * 4 + q] = g;
    }
    __syncthreads();

    // trim-flush with ADAPTIVE threshold; wave wv owns cols wv*4..wv*4+3,
    // 16 lanes per col. No barriers inside (same-wave ordering suffices).
    {
        const int j   = l >> 4;          // 0..3
        const int g16 = l & 15;
        const int d   = wv * 4 + j;
        const int n   = cnt[d];
        const float qm = bmaxs[d];
        const float T1 = qm - 1.0f, T2 = qm - 0.5f, T3 = qm - 0.25f;

        int c1 = 0, c2 = 0, c3 = 0;
        if (n <= LCAP) {
            for (int p = g16; p < n; p += 16) {
                float v = list[d][p];
                c1 += (v > T1); c2 += (v > T2); c3 += (v > T3);
            }
            // 16-lane butterfly (masks 1..8 stay within the col group)
#pragma unroll
            for (int mask = 1; mask <= 8; mask <<= 1) {
                c1 += __shfl_xor(c1, mask);
                c2 += __shfl_xor(c2, mask);
                c3 += __shfl_xor(c3, mask);
            }
        }
        float T = 0.0f; bool ok = false;
        if (n <= LCAP) {
            if      (c1 <= GCAP) { ok = true; T = T1; }
            else if (c2 <= GCAP) { ok = true; T = T2; }
            else if (c3 <= GCAP) { ok = true; T = T3; }
        }
        if (ok) {
            const size_t gbase = (((size_t)bh * 64 + d) * 4 + q) * GCAP;
            for (int p = g16; p < n; p += 16) {
                float v = list[d][p];
                if (v > T) {
                    int i = atomicAdd(&cnt2[d], 1);
                    if (i < GCAP) glist[gbase + i] = v;   // count<=GCAP by construction
                }
            }
        }
        if (g16 == 0) {
            const size_t gi = ((size_t)bh * 64 + d) * 4 + q;
            gcnt[gi] = ok ? cnt2[d] : SENT;
            qthr[gi] = T;
        }
    }
}

// ---------------------------------------------------------------- K2 ----
__global__ __launch_bounds__(1024)
void k2_apply(const float* __restrict__ x,
              const float* __restrict__ pmax,
              const int*   __restrict__ gcnt,
              const float* __restrict__ qthr,
              const float* __restrict__ glist,
              float* __restrict__ out)
{
    const int b  = blockIdx.x;      // 0..511
    const int bh = b >> 2;
    const int q  = b & 3;
    const int t  = threadIdx.x;
    const int l  = t & 63;
    const int wv = t >> 6;          // 0..15

    __shared__ float gmaxL[64];
    __shared__ float tauL[64];

    // ---- phase A: tau for the slab's 64 cols (wave wv: cols wv*4..+3) ----
    for (int cc4 = 0; cc4 < 4; ++cc4) {
        const int d   = wv * 4 + cc4;
        const int col = bh * 64 + d;
        const float g = fmaxf(fmaxf(pmax[col*4+0], pmax[col*4+1]),
                              fmaxf(pmax[col*4+2], pmax[col*4+3]));
        int cs[4]; bool ok = true;
#pragma unroll
        for (int qq = 0; qq < 4; ++qq) {
            cs[qq] = gcnt[col*4+qq];
            float th = qthr[col*4+qq];
            ok = ok && (cs[qq] <= GCAP) && (th <= g - 1.0f);
        }
        float tau = -1.0f;
        if (ok) {
            const float* __restrict__ L = glist + (size_t)col * 4 * GCAP;
            for (int it = 0; it < 64; ++it) {
                float sv = 0.f, cn = 0.f;
#pragma unroll
                for (int qq = 0; qq < 4; ++qq) {
                    for (int p = l; p < cs[qq]; p += 64) {
                        float z = L[qq * GCAP + p] - g;    // reference rounding
                        if (z > tau) { sv += z; cn += 1.f; }
                    }
                }
#pragma unroll
                for (int mask = 1; mask <= 32; mask <<= 1) {
                    sv += __shfl_xor(sv, mask);
                    cn += __shfl_xor(cn, mask);
                }
                if (cn < 0.5f) break;
                float tn = (sv - 1.0f) / cn;
                tn = fmaxf(tn, tau);
                if (tn == tau) break;                      // exact fixed point
                tau = tn;
            }
        } else {
            // correctness fallback (prob ~e^-14): strided column read
            const float* vb = x + (size_t)bh * 262144 + d;
            for (int it = 0; it < 64; ++it) {
                float sv = 0.f, cn = 0.f;
                for (int p = l; p < 4096; p += 64) {
                    float z = vb[(size_t)p * 64] - g;
                    if (z > tau) { sv += z; cn += 1.f; }
                }
#pragma unroll
                for (int mask = 1; mask <= 32; mask <<= 1) {
                    sv += __shfl_xor(sv, mask);
                    cn += __shfl_xor(cn, mask);
                }
                if (cn < 0.5f) break;
                float tn = (sv - 1.0f) / cn;
                tn = fmaxf(tn, tau);
                if (tn == tau) break;
                tau = tn;
            }
        }
        if (l == 0) { gmaxL[d] = g; tauL[d] = tau; }
    }
    __syncthreads();

    // ---- phase B: contiguous apply (same burst layout as K1), NT stores ----
    const int d4 = l & 15;
    f32x4 g4, t4;
    g4.x = gmaxL[d4*4+0]; g4.y = gmaxL[d4*4+1]; g4.z = gmaxL[d4*4+2]; g4.w = gmaxL[d4*4+3];
    t4.x = tauL[d4*4+0];  t4.y = tauL[d4*4+1];  t4.z = tauL[d4*4+2];  t4.w = tauL[d4*4+3];

    const f32x4* __restrict__ x4 = reinterpret_cast<const f32x4*>(x);
    f32x4* __restrict__ o4       = reinterpret_cast<f32x4*>(out);
    const size_t base = (size_t)bh * 65536 + (size_t)q * 16384
                      + (size_t)wv * 1024 + (size_t)l;
#pragma unroll
    for (int s = 0; s < 16; ++s) {
        f32x4 xv = x4[base + (size_t)s * 64];
        f32x4 o;
        o.x = fmaxf((xv.x - g4.x) - t4.x, 0.f);
        o.y = fmaxf((xv.y - g4.y) - t4.y, 0.f);
        o.z = fmaxf((xv.z - g4.z) - t4.z, 0.f);
        o.w = fmaxf((xv.w - g4.w) - t4.w, 0.f);
        __builtin_nontemporal_store(o, &o4[base + (size_t)s * 64]);
    }
}

// ------------------------------------------- fallback: fused (known-good) ----
#define C_CAP 256
__global__ __launch_bounds__(1024, 4)
void sparsemax_fused(const float* __restrict__ x, float* __restrict__ out)
{
    const int b = blockIdx.x, bh = b >> 2, dt = b & 3;
    const int t = threadIdx.x, lane = t & 63, wv = t >> 6, dq = t & 3, iblk = t >> 2;
    __shared__ float list[16][C_CAP];
    __shared__ float redbuf[256];
    __shared__ float gmaxT[16];
    __shared__ float tauLDS[16];
    __shared__ int   cnt[16];
    const f32x4* __restrict__ x4 = reinterpret_cast<const f32x4*>(x);
    f32x4* __restrict__ o4       = reinterpret_cast<f32x4*>(out);
    const size_t slabrow = (size_t)bh * 4096;
    const size_t idx0 = (slabrow + (size_t)iblk) * 16 + (size_t)(dt * 4) + (size_t)dq;
    f32x4 c[16];
#pragma unroll
    for (int s = 0; s < 16; ++s) c[s] = x4[idx0 + (size_t)s * 4096];
    f32x4 m = c[0];
#pragma unroll
    for (int s = 1; s < 16; ++s) {
        m.x = fmaxf(m.x, c[s].x); m.y = fmaxf(m.y, c[s].y);
        m.z = fmaxf(m.z, c[s].z); m.w = fmaxf(m.w, c[s].w);
    }
#pragma unroll
    for (int mask = 4; mask <= 32; mask <<= 1) {
        m.x = fmaxf(m.x, __shfl_xor(m.x, mask));
        m.y = fmaxf(m.y, __shfl_xor(m.y, mask));
        m.z = fmaxf(m.z, __shfl_xor(m.z, mask));
        m.w = fmaxf(m.w, __shfl_xor(m.w, mask));
    }
    if (lane < 4) {
        redbuf[wv*16 + lane*4 + 0] = m.x; redbuf[wv*16 + lane*4 + 1] = m.y;
        redbuf[wv*16 + lane*4 + 2] = m.z; redbuf[wv*16 + lane*4 + 3] = m.w;
    }
    __syncthreads();
    if (t < 16) {
        float g = redbuf[t];
#pragma unroll
        for (int w = 1; w < 16; ++w) g = fmaxf(g, redbuf[w*16 + t]);
        gmaxT[t] = g; cnt[t] = 0;
    }
    __syncthreads();
    const int j0 = dq << 2;
    f32x4 g4v;
    g4v.x = gmaxT[j0+0]; g4v.y = gmaxT[j0+1]; g4v.z = gmaxT[j0+2]; g4v.w = gmaxT[j0+3];
#pragma unroll
    for (int s = 0; s < 16; ++s) {
        float zx = c[s].x - g4v.x, zy = c[s].y - g4v.y, zz = c[s].z - g4v.z, zw = c[s].w - g4v.w;
        if (zx > -1.0f) { int p = atomicAdd(&cnt[j0+0],1); if (p < C_CAP) list[j0+0][p] = zx; }
        if (zy > -1.0f) { int p = atomicAdd(&cnt[j0+1],1); if (p < C_CAP) list[j0+1][p] = zy; }
        if (zz > -1.0f) { int p = atomicAdd(&cnt[j0+2],1); if (p < C_CAP) list[j0+2][p] = zz; }
        if (zw > -1.0f) { int p = atomicAdd(&cnt[j0+3],1); if (p < C_CAP) list[j0+3][p] = zw; }
    }
    __syncthreads();
    {
        const int j = wv; const int n = cnt[j]; float tau = -1.0f;
        if (n <= C_CAP) {
            for (int it = 0; it < 100; ++it) {
                float sv = 0.f, cc = 0.f;
                for (int p = lane; p < n; p += 64) {
                    float v = list[j][p];
                    if (v > tau) { sv += v; cc += 1.f; }
                }
#pragma unroll
                for (int mask = 1; mask <= 32; mask <<= 1) { sv += __shfl_xor(sv, mask); cc += __shfl_xor(cc, mask); }
                if (cc < 0.5f) break;
                float tn = (sv - 1.0f) / cc; tn = fmaxf(tn, tau);
                if (tn == tau) break; tau = tn;
            }
        } else {
            const float g = gmaxT[j];
            const float* vb = x + slabrow * 64 + (size_t)(dt * 16 + j);
            for (int it = 0; it < 100; ++it) {
                float sv = 0.f, cc = 0.f;
                for (int p = lane; p < 4096; p += 64) {
                    float v = vb[(size_t)p * 64] - g;
                    if (v > tau) { sv += v; cc += 1.f; }
                }
#pragma unroll
                for (int mask = 1; mask <= 32; mask <<= 1) { sv += __shfl_xor(sv, mask); cc += __shfl_xor(cc, mask); }
                if (cc < 0.5f) break;
                float tn = (sv - 1.0f) / cc; tn = fmaxf(tn, tau);
                if (tn == tau) break; tau = tn;
            }
        }
        if (lane == 0) tauLDS[j] = tau;
    }
    __syncthreads();
    f32x4 tau4;
    tau4.x = tauLDS[j0+0]; tau4.y = tauLDS[j0+1]; tau4.z = tauLDS[j0+2]; tau4.w = tauLDS[j0+3];
#pragma unroll
    for (int s = 0; s < 16; ++s) {
        f32x4 o;
        o.x = fmaxf((c[s].x - g4v.x) - tau4.x, 0.f);
        o.y = fmaxf((c[s].y - g4v.y) - tau4.y, 0.f);
        o.z = fmaxf((c[s].z - g4v.z) - tau4.z, 0.f);
        o.w = fmaxf((c[s].w - g4v.w) - tau4.w, 0.f);
        o4[idx0 + (size_t)s * 4096] = o;
    }
}

extern "C" void kernel_launch(void* const* d_in, const int* in_sizes, int n_in,
                              void* d_out, int out_size, void* d_ws, size_t ws_size,
                              hipStream_t stream)
{
    (void)n_in; (void)out_size;
    const float* x = (const float*)d_in[0];
    float* out     = (float*)d_out;
    const int total = in_sizes[0];            // 33554432
    const int slabs = total / (4096 * 64);    // 128
    const int ncols = slabs * 64;             // 8192

    const size_t off_pmax  = 0;                                   // f[ncols*4]
    const size_t off_gcnt  = off_pmax + (size_t)ncols * 4 * 4;    // i[ncols*4]
    const size_t off_qthr  = off_gcnt + (size_t)ncols * 4 * 4;    // f[ncols*4]
    const size_t off_glist = off_qthr + (size_t)ncols * 4 * 4;    // f[ncols*4*GCAP]
    const size_t ws_need   = off_glist + (size_t)ncols * 4 * GCAP * 4;

    if (ws_size < ws_need) {
        hipLaunchKernelGGL(sparsemax_fused, dim3(slabs * 4), dim3(1024), 0, stream, x, out);
        return;
    }

    char* ws = (char*)d_ws;
    float* pmax  = (float*)(ws + off_pmax);
    int*   gcnt  = (int*)  (ws + off_gcnt);
    float* qthr  = (float*)(ws + off_qthr);
    float* glist = (float*)(ws + off_glist);

    hipLaunchKernelGGL(k1_extract, dim3(slabs * 4), dim3(1024), 0, stream,
                       x, pmax, gcnt, qthr, glist);
    hipLaunchKernelGGL(k2_apply, dim3(slabs * 4), dim3(1024), 0, stream,
                       x, pmax, gcnt, qthr, glist, out);
}

// Round 11
// 281.166 us; speedup vs baseline: 1.3522x; 1.3522x over previous
//
#include <hip/hip_runtime.h>

// sparsemax over axis=2 of x[8][16][4096][64] (fp32) — 5 minimal streaming passes.
//
// Evidence trail: R7 grid-stride apply (2048x256, 1 f4 load/iter) is the only
// shape measured fast (~5 TB/s). R9/R10's 1024-thread chunk blocks with fused
// reduce/extract/newton phases sustain only 1.6-2.5 TB/s and hide attribution.
// R11: every pass is single-purpose in the proven shape, profiled separately.
//
// P0: gmax=-inf, gcnt=0.
// P1: per-(slab,256-row-chunk) col-max -> 1 global atomicMaxF per col/block.
// P2: re-read, extract v > gmax-1 (exact global threshold, ~14/col total)
//     -> glist[col][<=256] global append.
// P3: one wave per col: Newton-from-below on z = v - gmax (exact, piecewise
//     linear, bitwise fixed-point stop; absmax 0.0 in R6/R7/R9/R10).
// P4: R7-proven apply: out = relu((x - gmax) - tau).
//
// ws (8.42 MB): gmax f[8192] | tau f[8192] | gcnt i[8192] | glist f[8192*256].
// ws too small -> R6 fused single-kernel fallback (known-good, 113us).

#define PCAP 256

typedef float f32x4 __attribute__((ext_vector_type(4)));

__device__ __forceinline__ void atomicMaxF(float* a, float v) {
    // sign-split trick: int ordering matches floats >=0; uint-min handles negatives.
    if (v >= 0.0f) atomicMax((int*)a, __float_as_int(v));
    else           atomicMin((unsigned int*)a, __float_as_uint(v));
}

// ---------------------------------------------------------------- P0 ----
__global__ __launch_bounds__(256)
void p0_init(float* __restrict__ gmax, int* __restrict__ gcnt, int ncols)
{
    int i = blockIdx.x * 256 + threadIdx.x;
    if (i < ncols) { gmax[i] = -__builtin_huge_valf(); gcnt[i] = 0; }
}

// ---------------------------------------------------------------- P1 ----
// block = (slab, 256-row chunk): 64KB contiguous. thread t always sees d4=t&15.
__global__ __launch_bounds__(256)
void p1_max(const float* __restrict__ x, float* __restrict__ gmax)
{
    const int b    = blockIdx.x;        // 0..2047
    const int slab = b >> 4;
    const int rb   = b & 15;
    const int t    = threadIdx.x;       // 0..255
    const int l    = t & 63;
    const int wv   = t >> 6;            // 0..3
    const int d4   = t & 15;

    const f32x4* __restrict__ x4 = reinterpret_cast<const f32x4*>(x);
    const size_t base = (size_t)slab * 65536 + (size_t)rb * 4096;

    f32x4 m;
    m.x = m.y = m.z = m.w = -__builtin_huge_valf();
    for (int k = 0; k < 16; ++k) {                  // one f4 live per iteration
        f32x4 v = x4[base + (size_t)k * 256 + t];
        m.x = fmaxf(m.x, v.x);
        m.y = fmaxf(m.y, v.y);
        m.z = fmaxf(m.z, v.z);
        m.w = fmaxf(m.w, v.w);
    }
    // wave reduce within d4 class (xor 16,32 keep l&15)
#pragma unroll
    for (int mask = 16; mask <= 32; mask <<= 1) {
        m.x = fmaxf(m.x, __shfl_xor(m.x, mask));
        m.y = fmaxf(m.y, __shfl_xor(m.y, mask));
        m.z = fmaxf(m.z, __shfl_xor(m.z, mask));
        m.w = fmaxf(m.w, __shfl_xor(m.w, mask));
    }
    __shared__ float red[4][64];
    if (l < 16) {
        red[wv][l * 4 + 0] = m.x;
        red[wv][l * 4 + 1] = m.y;
        red[wv][l * 4 + 2] = m.z;
        red[wv][l * 4 + 3] = m.w;
    }
    __syncthreads();
    if (t < 64) {
        float g = fmaxf(fmaxf(red[0][t], red[1][t]), fmaxf(red[2][t], red[3][t]));
        atomicMaxF(&gmax[slab * 64 + t], g);
    }
}

// ---------------------------------------------------------------- P2 ----
__global__ __launch_bounds__(256)
void p2_extract(const float* __restrict__ x, const float* __restrict__ gmax,
                int* __restrict__ gcnt, float* __restrict__ glist)
{
    const int b    = blockIdx.x;
    const int slab = b >> 4;
    const int rb   = b & 15;
    const int t    = threadIdx.x;
    const int d4   = t & 15;

    const f32x4* __restrict__ x4  = reinterpret_cast<const f32x4*>(x);
    const f32x4* __restrict__ g4p = reinterpret_cast<const f32x4*>(gmax);
    const size_t base = (size_t)slab * 65536 + (size_t)rb * 4096;

    const f32x4 g = g4p[slab * 16 + d4];
    const float Tx = g.x - 1.0f, Ty = g.y - 1.0f, Tz = g.z - 1.0f, Tw = g.w - 1.0f;
    const int col0 = slab * 64 + d4 * 4;

    for (int k = 0; k < 16; ++k) {
        f32x4 v = x4[base + (size_t)k * 256 + t];
        // exact support superset: tau >= gmax-1 always, so nothing below matters
        if (v.x > Tx) { int i = atomicAdd(&gcnt[col0+0], 1); if (i < PCAP) glist[(size_t)(col0+0)*PCAP + i] = v.x; }
        if (v.y > Ty) { int i = atomicAdd(&gcnt[col0+1], 1); if (i < PCAP) glist[(size_t)(col0+1)*PCAP + i] = v.y; }
        if (v.z > Tz) { int i = atomicAdd(&gcnt[col0+2], 1); if (i < PCAP) glist[(size_t)(col0+2)*PCAP + i] = v.z; }
        if (v.w > Tw) { int i = atomicAdd(&gcnt[col0+3], 1); if (i < PCAP) glist[(size_t)(col0+3)*PCAP + i] = v.w; }
    }
}

// ---------------------------------------------------------------- P3 ----
__global__ __launch_bounds__(1024)
void p3_newton(const float* __restrict__ x, const float* __restrict__ gmax,
               const int* __restrict__ gcnt, const float* __restrict__ glist,
               float* __restrict__ tauo)
{
    const int col = blockIdx.x * 16 + (threadIdx.x >> 6);  // 0..8191
    const int l   = threadIdx.x & 63;
    const float g = gmax[col];
    const int   n = gcnt[col];

    float tau = -1.0f;
    if (n <= PCAP) {
        const float* __restrict__ L = glist + (size_t)col * PCAP;
        for (int it = 0; it < 64; ++it) {
            float sv = 0.f, cn = 0.f;
            for (int p = l; p < n; p += 64) {
                float z = L[p] - g;                 // reference rounding (x - max)
                if (z > tau) { sv += z; cn += 1.f; }
            }
#pragma unroll
            for (int mask = 1; mask <= 32; mask <<= 1) {
                sv += __shfl_xor(sv, mask);
                cn += __shfl_xor(cn, mask);
            }
            if (cn < 0.5f) break;
            float tn = (sv - 1.0f) / cn;
            tn = fmaxf(tn, tau);                    // monotone ascent from below
            if (tn == tau) break;                   // exact fixed point
            tau = tn;
        }
    } else {
        // correctness fallback (P ~ 0): strided full-column read
        const int slab = col >> 6, d = col & 63;
        const float* vb = x + (size_t)slab * 262144 + d;
        for (int it = 0; it < 64; ++it) {
            float sv = 0.f, cn = 0.f;
            for (int p = l; p < 4096; p += 64) {
                float z = vb[(size_t)p * 64] - g;
                if (z > tau) { sv += z; cn += 1.f; }
            }
#pragma unroll
            for (int mask = 1; mask <= 32; mask <<= 1) {
                sv += __shfl_xor(sv, mask);
                cn += __shfl_xor(cn, mask);
            }
            if (cn < 0.5f) break;
            float tn = (sv - 1.0f) / cn;
            tn = fmaxf(tn, tau);
            if (tn == tau) break;
            tau = tn;
        }
    }
    if (l == 0) tauo[col] = tau;
}

// ---------------------------------------------------------------- P4 ----
// verbatim R7 k3_apply shape (the one dispatch measured fast).
__global__ __launch_bounds__(256)
void p4_apply(const float* __restrict__ x,
              const float* __restrict__ gmax_in,
              const float* __restrict__ tau_in,
              float* __restrict__ out, int n4)
{
    const f32x4* __restrict__ x4 = reinterpret_cast<const f32x4*>(x);
    const f32x4* __restrict__ g4 = reinterpret_cast<const f32x4*>(gmax_in);
    const f32x4* __restrict__ t4 = reinterpret_cast<const f32x4*>(tau_in);
    f32x4* __restrict__ o4       = reinterpret_cast<f32x4*>(out);

    const int stride = gridDim.x * 256;
    for (int f = blockIdx.x * 256 + threadIdx.x; f < n4; f += stride) {
        const int d4 = f & 15;
        const int bh = f >> 16;
        const int v  = bh * 16 + d4;
        f32x4 xv = x4[f];
        f32x4 g  = g4[v];
        f32x4 tv = t4[v];
        f32x4 o;
        o.x = fmaxf((xv.x - g.x) - tv.x, 0.f);
        o.y = fmaxf((xv.y - g.y) - tv.y, 0.f);
        o.z = fmaxf((xv.z - g.z) - tv.z, 0.f);
        o.w = fmaxf((xv.w - g.w) - tv.w, 0.f);
        o4[f] = o;
    }
}

// ------------------------------------------- fallback: fused (known-good) ----
#define C_CAP 256
__global__ __launch_bounds__(1024, 4)
void sparsemax_fused(const float* __restrict__ x, float* __restrict__ out)
{
    const int b = blockIdx.x, bh = b >> 2, dt = b & 3;
    const int t = threadIdx.x, lane = t & 63, wv = t >> 6, dq = t & 3, iblk = t >> 2;
    __shared__ float list[16][C_CAP];
    __shared__ float redbuf[256];
    __shared__ float gmaxT[16];
    __shared__ float tauLDS[16];
    __shared__ int   cnt[16];
    const f32x4* __restrict__ x4 = reinterpret_cast<const f32x4*>(x);
    f32x4* __restrict__ o4       = reinterpret_cast<f32x4*>(out);
    const size_t slabrow = (size_t)bh * 4096;
    const size_t idx0 = (slabrow + (size_t)iblk) * 16 + (size_t)(dt * 4) + (size_t)dq;
    f32x4 c[16];
#pragma unroll
    for (int s = 0; s < 16; ++s) c[s] = x4[idx0 + (size_t)s * 4096];
    f32x4 m = c[0];
#pragma unroll
    for (int s = 1; s < 16; ++s) {
        m.x = fmaxf(m.x, c[s].x); m.y = fmaxf(m.y, c[s].y);
        m.z = fmaxf(m.z, c[s].z); m.w = fmaxf(m.w, c[s].w);
    }
#pragma unroll
    for (int mask = 4; mask <= 32; mask <<= 1) {
        m.x = fmaxf(m.x, __shfl_xor(m.x, mask));
        m.y = fmaxf(m.y, __shfl_xor(m.y, mask));
        m.z = fmaxf(m.z, __shfl_xor(m.z, mask));
        m.w = fmaxf(m.w, __shfl_xor(m.w, mask));
    }
    if (lane < 4) {
        redbuf[wv*16 + lane*4 + 0] = m.x; redbuf[wv*16 + lane*4 + 1] = m.y;
        redbuf[wv*16 + lane*4 + 2] = m.z; redbuf[wv*16 + lane*4 + 3] = m.w;
    }
    __syncthreads();
    if (t < 16) {
        float g = redbuf[t];
#pragma unroll
        for (int w = 1; w < 16; ++w) g = fmaxf(g, redbuf[w*16 + t]);
        gmaxT[t] = g; cnt[t] = 0;
    }
    __syncthreads();
    const int j0 = dq << 2;
    f32x4 g4v;
    g4v.x = gmaxT[j0+0]; g4v.y = gmaxT[j0+1]; g4v.z = gmaxT[j0+2]; g4v.w = gmaxT[j0+3];
#pragma unroll
    for (int s = 0; s < 16; ++s) {
        float zx = c[s].x - g4v.x, zy = c[s].y - g4v.y, zz = c[s].z - g4v.z, zw = c[s].w - g4v.w;
        if (zx > -1.0f) { int p = atomicAdd(&cnt[j0+0],1); if (p < C_CAP) list[j0+0][p] = zx; }
        if (zy > -1.0f) { int p = atomicAdd(&cnt[j0+1],1); if (p < C_CAP) list[j0+1][p] = zy; }
        if (zz > -1.0f) { int p = atomicAdd(&cnt[j0+2],1); if (p < C_CAP) list[j0+2][p] = zz; }
        if (zw > -1.0f) { int p = atomicAdd(&cnt[j0+3],1); if (p < C_CAP) list[j0+3][p] = zw; }
    }
    __syncthreads();
    {
        const int j = wv; const int n = cnt[j]; float tau = -1.0f;
        if (n <= C_CAP) {
            for (int it = 0; it < 100; ++it) {
                float sv = 0.f, cc = 0.f;
                for (int p = lane; p < n; p += 64) {
                    float v = list[j][p];
                    if (v > tau) { sv += v; cc += 1.f; }
                }
#pragma unroll
                for (int mask = 1; mask <= 32; mask <<= 1) { sv += __shfl_xor(sv, mask); cc += __shfl_xor(cc, mask); }
                if (cc < 0.5f) break;
                float tn = (sv - 1.0f) / cc; tn = fmaxf(tn, tau);
                if (tn == tau) break; tau = tn;
            }
        } else {
            const float g = gmaxT[j];
            const float* vb = x + slabrow * 64 + (size_t)(dt * 16 + j);
            for (int it = 0; it < 100; ++it) {
                float sv = 0.f, cc = 0.f;
                for (int p = lane; p < 4096; p += 64) {
                    float v = vb[(size_t)p * 64] - g;
                    if (v > tau) { sv += v; cc += 1.f; }
                }
#pragma unroll
                for (int mask = 1; mask <= 32; mask <<= 1) { sv += __shfl_xor(sv, mask); cc += __shfl_xor(cc, mask); }
                if (cc < 0.5f) break;
                float tn = (sv - 1.0f) / cc; tn = fmaxf(tn, tau);
                if (tn == tau) break; tau = tn;
            }
        }
        if (lane == 0) tauLDS[j] = tau;
    }
    __syncthreads();
    f32x4 tau4;
    tau4.x = tauLDS[j0+0]; tau4.y = tauLDS[j0+1]; tau4.z = tauLDS[j0+2]; tau4.w = tauLDS[j0+3];
#pragma unroll
    for (int s = 0; s < 16; ++s) {
        f32x4 o;
        o.x = fmaxf((c[s].x - g4v.x) - tau4.x, 0.f);
        o.y = fmaxf((c[s].y - g4v.y) - tau4.y, 0.f);
        o.z = fmaxf((c[s].z - g4v.z) - tau4.z, 0.f);
        o.w = fmaxf((c[s].w - g4v.w) - tau4.w, 0.f);
        o4[idx0 + (size_t)s * 4096] = o;
    }
}

extern "C" void kernel_launch(void* const* d_in, const int* in_sizes, int n_in,
                              void* d_out, int out_size, void* d_ws, size_t ws_size,
                              hipStream_t stream)
{
    (void)n_in; (void)out_size;
    const float* x = (const float*)d_in[0];
    float* out     = (float*)d_out;
    const int total = in_sizes[0];            // 33554432
    const int slabs = total / (4096 * 64);    // 128
    const int ncols = slabs * 64;             // 8192
    const int n4    = total / 4;

    const size_t off_gmax  = 0;                                   // f[ncols]
    const size_t off_tau   = off_gmax + (size_t)ncols * 4;        // f[ncols]
    const size_t off_gcnt  = off_tau  + (size_t)ncols * 4;        // i[ncols]
    const size_t off_glist = off_gcnt + (size_t)ncols * 4;        // f[ncols*PCAP]
    const size_t ws_need   = off_glist + (size_t)ncols * PCAP * 4;

    if (ws_size < ws_need) {
        hipLaunchKernelGGL(sparsemax_fused, dim3(slabs * 4), dim3(1024), 0, stream, x, out);
        return;
    }

    char* ws = (char*)d_ws;
    float* gmax  = (float*)(ws + off_gmax);
    float* tau   = (float*)(ws + off_tau);
    int*   gcnt  = (int*)  (ws + off_gcnt);
    float* glist = (float*)(ws + off_glist);

    hipLaunchKernelGGL(p0_init,    dim3((ncols + 255) / 256), dim3(256), 0, stream, gmax, gcnt, ncols);
    hipLaunchKernelGGL(p1_max,     dim3(slabs * 16), dim3(256), 0, stream, x, gmax);
    hipLaunchKernelGGL(p2_extract, dim3(slabs * 16), dim3(256), 0, stream, x, gmax, gcnt, glist);
    hipLaunchKernelGGL(p3_newton,  dim3(ncols / 16), dim3(1024), 0, stream, x, gmax, gcnt, glist, tau);
    hipLaunchKernelGGL(p4_apply,   dim3(2048), dim3(256), 0, stream, x, gmax, tau, out, n4);
}